// Round 4
// baseline (564.215 us; speedup 1.0000x reference)
//
#include <hip/hip_runtime.h>
#include <cstdint>

// Problem constants (LocalizedFiltering: B=4, S=4096, D=2048, DH=1024)
#define BB 4
#define SS 4096           // power of 2: t = r & 4095, b = r >> 12
#define DD 2048
#define DH 1024
#define MM (BB * SS)      // 16384 rows
#define EPSV 1e-6f

typedef unsigned short u16;
typedef __bf16 bf16x8 __attribute__((ext_vector_type(8)));
typedef float f32x4 __attribute__((ext_vector_type(4)));

// ---------- helpers ----------

__device__ __forceinline__ u16 f2bf(float f) {           // RNE f32 -> bf16 bits
    uint32_t u = __float_as_uint(f);
    u += 0x7fffu + ((u >> 16) & 1u);
    return (u16)(u >> 16);
}

// async global->LDS, 16B per lane. LDS dest is wave-uniform base + lane*16.
__device__ __forceinline__ void async16(const void* g, void* l) {
    __builtin_amdgcn_global_load_lds(
        (const __attribute__((address_space(1))) uint32_t*)g,
        (__attribute__((address_space(3))) uint32_t*)l,
        16, 0, 0);
}

#define FENCE asm volatile("" ::: "memory")

// ---------- elementwise converts / packs ----------

__global__ void cvt_f32_bf16(const float* __restrict__ in, u16* __restrict__ out, long n4) {
    long i = (long)blockIdx.x * blockDim.x + threadIdx.x;
    if (i >= n4) return;
    float4 v = *(const float4*)(in + i * 4);
    ushort4 o;
    o.x = f2bf(v.x); o.y = f2bf(v.y); o.z = f2bf(v.z); o.w = f2bf(v.w);
    *(ushort4*)(out + i * 4) = o;
}

// w [Nr, Dd, 2] f32 (tap-interleaved) -> out [Nr, 2*Dd] bf16 with tap0 cols [0,Dd), tap1 [Dd,2Dd)
__global__ void pack_w(const float* __restrict__ in, u16* __restrict__ out, int dshift) {
    int idx = blockIdx.x * 256 + threadIdx.x;   // pair index: e*Dd + d
    int Dd = 1 << dshift;
    int e = idx >> dshift;
    int d = idx & (Dd - 1);
    float2 v = *(const float2*)(in + (long)idx * 2);
    long rowbase = (long)e * (Dd * 2);
    out[rowbase + d] = f2bf(v.x);          // tap 0 (prev timestep)
    out[rowbase + Dd + d] = f2bf(v.y);     // tap 1 (current timestep)
}

// ---------- shifted 2-tap GEMM: 256x256 tile, 8-wave, ring-4 + register double-buffer ----------
//
// ROUND-4 STRUCTURE: round-3's per-window accounting (3176 cyc measured vs
// 1242 MFMA + 1152 LDS-read) showed the LDS-read burst and MFMA burst
// SERIALIZE because each window's MFMAs consume that same window's reads.
// Fix: double-buffered fragment registers. Window W_i:
//   { reads(i+1) -> alternate frag set   (12 ds_read_b128)
//     stage(i+3) -> slot (i+3)&3         (4 global_load_lds)
//     MFMA(i) on current frag set        (32 mfma; lgkm wait covers only the
//                                         OLD reads - a full window of slack)
//     s_waitcnt vmcnt(4) ; s_barrier }
// The new reads + staging execute UNDER the MFMA burst (independent regs).
//
// Hazard audit:
//  WAR: stage(u) issues in W_{u-3}, writes slot u&3 = (u-4)&3's ring slot.
//    Last readers = reads(u-4), prefetched in W_{u-5}, lgkm-drained by
//    MFMA(u-4) in W_{u-4}, i.e. before every wave passed B_{u-4} < W_{u-3}. OK
//  RAW: reads(j+2) in W_{j+1} need stage(j+2) landed: W_j's vmcnt(4) drains it
//    (outstanding there = stage(j+3), stage(j+2) = 8 loads -> wait to 4).
//    Flight time = 2 windows (~2600+ cyc) >> 900-cyc HBM latency.
//  Cross-wave visibility of staged slices: vmcnt precedes the barrier. OK
// Prologue: stage 0,1,2; vmcnt(4) (0,1 landed); barrier; reads(0)->set A.
// Tail: W_{NS-4} stages NS-1 (vmcnt4); W_{NS-3} vmcnt(0)+bar; W_{NS-2} reads
//   only; W_{NS-1} MFMA only. NS-4 even (124/60) keeps A/B parity.
//
// LDS (128 KiB): ring of 4 K-half slots per matrix, slot = step & 3.
//   A slot u at elems [u*8192, +8192): 256 rows x 32 k-elems (row r at r*32+k).
//   B slot u at 32768 + u*8192, same shape (rows = output cols).
// Swizzle (verified conflict-free rounds 1-3): 16B-slot s of row r holds
//   global chunk s ^ ((r>>1)&3); staged via pre-swizzled GLOBAL address
//   (global_load_lds dest is linear base+lane*16), read with the same XOR.
//
// C[r,n] = sum_{k<KD} Bt[n,k]*Aprev[r,k] + sum_{k<KD} Bt[n,KD+k]*Acur[r,k]
// Aprev row r = (r%S==0) ? cache[r/S] : A[r-1]
// Step u sources Aprev when u < NT (K-offset u*32 < KD), else Acur at u*32-KD.
// MODE 1: out bf16 [M,NN] + bias; rows with t==S-1 also stored f32 to lf2out
// MODE 2: out f32  [M,NN] + bias + residual xres
template <int KD, int MODE>
__launch_bounds__(512, 2)
__global__ void gemm2tap(const u16* __restrict__ A,       // [M, KD] bf16
                         const u16* __restrict__ cache,   // [B, KD] bf16
                         const u16* __restrict__ Bt,      // [NN, 2*KD] bf16
                         const float* __restrict__ bias,  // [NN]
                         u16* __restrict__ obf,           // MODE 1
                         float* __restrict__ lf2out,      // MODE 1
                         const float* __restrict__ xres,  // MODE 2
                         float* __restrict__ yout)        // MODE 2
{
    constexpr int KTOT = 2 * KD;
    constexpr int NT = KTOT / 64;      // K-tiles of 64
    constexpr int NS = 2 * NT;         // K-half steps of 32
    constexpr int NN = (MODE == 1) ? DH : DD;
    static_assert(NS % 4 == 0 && NS >= 8, "ring-4 schedule needs NS % 4 == 0, NS >= 8");
    static_assert(((NS - 4) & 1) == 0, "A/B frag parity needs even main-loop window count");

    const int tid = threadIdx.x;
    const int lane = tid & 63;
    const int wave = tid >> 6;         // 8 waves: wm = wave>>2 (2), wn = wave&3 (4)
    const int bm = blockIdx.x;
    const int bn = blockIdx.y;

    __shared__ __align__(16) u16 sm[65536];   // 128 KiB

    // ---- staging addressing ----
    const int srow = wave * 16 + (lane >> 2);          // row within 128-row half
    const int skc  = (lane & 3) ^ ((lane >> 3) & 3);   // pre-swizzled global chunk
    const int sRowA = wave * 512;                      // wave-uniform LDS elem offset

    const u16 *aPrev0, *aPrev1, *aCur0, *aCur1, *bPtr0, *bPtr1;
    {
        long r0 = (long)bm * 256 + srow;
        long r1 = r0 + 128;
        aCur0 = A + r0 * KD + skc * 8;
        aCur1 = A + r1 * KD + skc * 8;
        aPrev0 = ((((int)r0) & (SS - 1)) == 0) ? (cache + (r0 >> 12) * KD + skc * 8)
                                               : (A + (r0 - 1) * KD + skc * 8);
        aPrev1 = ((((int)r1) & (SS - 1)) == 0) ? (cache + (r1 >> 12) * KD + skc * 8)
                                               : (A + (r1 - 1) * KD + skc * 8);
        long n0l = (long)bn * 256 + srow;
        bPtr0 = Bt + n0l * KTOT + skc * 8;
        bPtr1 = Bt + (n0l + 128) * KTOT + skc * 8;
    }

    // stage K-half step U_ into ring slot U_&3 (A rows 0..127 then 128..255; B same)
#define STAGE(U_) do {                                                         \
        const int _u = (U_);                                                   \
        const int _sl = _u & 3;                                                \
        const u16 *_g0, *_g1;                                                  \
        if (_u < NT) { _g0 = aPrev0 + _u * 32; _g1 = aPrev1 + _u * 32; }       \
        else { _g0 = aCur0 + (_u - NT) * 32; _g1 = aCur1 + (_u - NT) * 32; }   \
        async16(_g0, sm + _sl * 8192 + sRowA);                                 \
        async16(_g1, sm + _sl * 8192 + 4096 + sRowA);                          \
        async16(bPtr0 + _u * 32, sm + 32768 + _sl * 8192 + sRowA);             \
        async16(bPtr1 + _u * 32, sm + 32768 + _sl * 8192 + 4096 + sRowA);      \
    } while (0)

    // ---- fragment read addressing ----
    const int frow = lane & 15;
    const int fquad = lane >> 4;
    const int wm128 = (wave >> 2) * 128;
    const int wn64  = (wave & 3) * 64;
    const int fq8s = (fquad ^ ((frow >> 1) & 3)) * 8;  // swizzled 16B chunk (elems)
    const int afb = (wm128 + frow) * 32 + fq8s;
    const int bfb = (wn64 + frow) * 32 + fq8s;

    f32x4 acc[8][4];
#pragma unroll
    for (int i = 0; i < 8; ++i)
#pragma unroll
        for (int j = 0; j < 4; ++j)
            acc[i][j] = (f32x4){0.f, 0.f, 0.f, 0.f};

    // double-buffered fragment sets
    bf16x8 afA[8], bqA[4], afB[8], bqB[4];

#define READS(SET_, RSLOT_) do {                                               \
    const u16* _aro = sm + (RSLOT_) * 8192;                                    \
    const u16* _bro = sm + 32768 + (RSLOT_) * 8192;                            \
    _Pragma("unroll")                                                          \
    for (int nf = 0; nf < 4; ++nf)                                             \
        bq##SET_[nf] = *(const bf16x8*)(_bro + bfb + nf * 512);                \
    _Pragma("unroll")                                                          \
    for (int mf = 0; mf < 8; ++mf)                                             \
        af##SET_[mf] = *(const bf16x8*)(_aro + afb + mf * 512);                \
} while (0)

#define MFMA_(D_, A_, B_) D_ = __builtin_amdgcn_mfma_f32_16x16x32_bf16(A_, B_, D_, 0, 0, 0)

#define MFMAS(SET_) do {                                                       \
    __builtin_amdgcn_s_setprio(1);                                             \
    _Pragma("unroll")                                                          \
    for (int mf = 0; mf < 8; ++mf)                                             \
        _Pragma("unroll")                                                      \
        for (int nf = 0; nf < 4; ++nf)                                         \
            MFMA_(acc[mf][nf], af##SET_[mf], bq##SET_[nf]);                    \
    __builtin_amdgcn_s_setprio(0);                                             \
} while (0)

    // Window: prefetch reads for next step (alt set), stage 3 ahead, MFMA current.
#define WIN(RSLOT_, RSET_, MSET_, SU_, DOSTG_, VMS_, DOBAR_)                   \
  {                                                                            \
    READS(RSET_, (RSLOT_));                                                    \
    if (DOSTG_) STAGE((SU_));                                                  \
    MFMAS(MSET_);                                                              \
    asm volatile(VMS_ ::: "memory");                                           \
    if (DOBAR_) { __builtin_amdgcn_s_barrier(); FENCE; }                       \
  }

    // ---- prologue: stage steps 0,1,2 (12 loads) in issue order; preload set A ----
    STAGE(0); FENCE;
    STAGE(1); FENCE;
    STAGE(2);
    asm volatile("s_waitcnt vmcnt(4)" ::: "memory");   // steps 0 and 1 landed
    FENCE; __builtin_amdgcn_s_barrier(); FENCE;
    READS(A, 0);

    // ---- main loop: windows 0 .. NS-5 (uniform: stage +3, vmcnt(4), barrier) ----
    for (int s = 0; s < NS - 4; s += 2) {
        WIN((s + 1) & 3, B, A, s + 3, 1, "s_waitcnt vmcnt(4)", 1);
        WIN((s + 2) & 3, A, B, s + 4, 1, "s_waitcnt vmcnt(4)", 1);
    }
    // ---- peeled tail: windows NS-4 .. NS-1 (NS-4 even -> current set is A) ----
    WIN((NS - 3) & 3, B, A, NS - 1, 1, "s_waitcnt vmcnt(4)", 1);   // last stage
    WIN((NS - 2) & 3, A, B, 0, 0, "s_waitcnt vmcnt(0)", 1);        // drain staging
    WIN((NS - 1) & 3, B, A, 0, 0, "", 0);                          // last reads
    MFMAS(B);                                                      // final step

#undef WIN
#undef MFMAS
#undef READS
#undef STAGE

    // ---- epilogue; C/D layout: col = lane&15, row = (lane>>4)*4 + v ----
    const long m0 = (long)bm * 256 + wm128;
    const int n0 = bn * 256 + wn64;
#pragma unroll
    for (int mf = 0; mf < 8; ++mf) {
#pragma unroll
        for (int nf = 0; nf < 4; ++nf) {
            const int n = n0 + nf * 16 + frow;
            const float bv = bias[n];
#pragma unroll
            for (int v = 0; v < 4; ++v) {
                const long m = m0 + mf * 16 + fquad * 4 + v;
                float val = acc[mf][nf][v] + bv;
                if (MODE == 1) {
                    obf[m * NN + n] = f2bf(val);
                    if ((((int)m) & (SS - 1)) == (SS - 1))
                        lf2out[(m >> 12) * NN + n] = val;   // new lf2 cache (f32)
                } else {
                    val += xres[m * NN + n];                // residual in f32
                    yout[m * NN + n] = val;
                }
            }
        }
    }
}

// ---------- RMSNorm (in-place on d_out rows) ----------

__global__ void rmsnorm_inplace(float* __restrict__ y, const float* __restrict__ lnw) {
    const long r = blockIdx.x;
    float* row = y + r * DD;
    const int tid = threadIdx.x;

    float4 v0 = *(float4*)(row + tid * 4);
    float4 v1 = *(float4*)(row + 1024 + tid * 4);
    float s = v0.x * v0.x + v0.y * v0.y + v0.z * v0.z + v0.w * v0.w
            + v1.x * v1.x + v1.y * v1.y + v1.z * v1.z + v1.w * v1.w;
#pragma unroll
    for (int off = 32; off; off >>= 1) s += __shfl_xor(s, off, 64);

    __shared__ float red[4];
    if ((tid & 63) == 0) red[tid >> 6] = s;
    __syncthreads();
    float tot = red[0] + red[1] + red[2] + red[3];
    float inv = rsqrtf(tot * (1.0f / DD) + EPSV);

    float4 w0 = *(const float4*)(lnw + tid * 4);
    float4 w1 = *(const float4*)(lnw + 1024 + tid * 4);
    v0.x *= inv * w0.x; v0.y *= inv * w0.y; v0.z *= inv * w0.z; v0.w *= inv * w0.w;
    v1.x *= inv * w1.x; v1.y *= inv * w1.y; v1.z *= inv * w1.z; v1.w *= inv * w1.w;
    *(float4*)(row + tid * 4) = v0;
    *(float4*)(row + 1024 + tid * 4) = v1;
}

// lf1 = x[:, S-1, :]  (f32 copy, B*D = 8192 elems)
__global__ void lf1_copy(const float* __restrict__ x, float* __restrict__ out) {
    int idx = blockIdx.x * 256 + threadIdx.x;   // 0..8191
    int b = idx >> 11;
    int d = idx & (DD - 1);
    out[idx] = x[((long)b * SS + (SS - 1)) * DD + d];
}

// ---------- launch ----------

extern "C" void kernel_launch(void* const* d_in, const int* in_sizes, int n_in,
                              void* d_out, int out_size, void* d_ws, size_t ws_size,
                              hipStream_t stream) {
    const float* x    = (const float*)d_in[0];   // [M, D]
    const float* lf1c = (const float*)d_in[1];   // [B, D]
    const float* lf2c = (const float*)d_in[2];   // [B, DH]
    const float* w1   = (const float*)d_in[3];   // [DH, D, 2]
    const float* b1   = (const float*)d_in[4];   // [DH]
    const float* w2   = (const float*)d_in[5];   // [D, DH, 2]
    const float* b2   = (const float*)d_in[6];   // [D]
    const float* lnw  = (const float*)d_in[7];   // [D]

    float* out    = (float*)d_out;                        // lf_output [M, D]
    float* lf1out = out + (long)MM * DD;                  // [B, D]
    float* lf2out = lf1out + (long)BB * DD;               // [B, DH]

    char* ws = (char*)d_ws;
    u16* Xbf  = (u16*)ws; ws += (long)MM * DD * 2;        // 67.1 MB
    u16* o1bf = (u16*)ws; ws += (long)MM * DH * 2;        // 33.6 MB
    u16* W1b  = (u16*)ws; ws += (long)DH * (2 * DD) * 2;  // 8.4 MB
    u16* W2b  = (u16*)ws; ws += (long)DD * (2 * DH) * 2;  // 8.4 MB
    u16* c1   = (u16*)ws; ws += (long)BB * DD * 2;
    u16* c2   = (u16*)ws; ws += (long)BB * DH * 2;

    // 1) converts & weight packing
    cvt_f32_bf16<<<32768, 256, 0, stream>>>(x, Xbf, (long)MM * DD / 4);
    cvt_f32_bf16<<<8, 256, 0, stream>>>(lf1c, c1, (long)BB * DD / 4);
    cvt_f32_bf16<<<4, 256, 0, stream>>>(lf2c, c2, (long)BB * DH / 4);
    pack_w<<<(DH * DD) / 256, 256, 0, stream>>>(w1, W1b, 11);   // Dd = D = 2048
    pack_w<<<(DD * DH) / 256, 256, 0, stream>>>(w2, W2b, 10);   // Dd = DH = 1024

    // 2) conv1 GEMM: [M, 2D] x [2D, DH] -> o1 bf16 (+ lf2 rows f32)
    gemm2tap<DD, 1><<<dim3(MM / 256, DH / 256), 512, 0, stream>>>(
        Xbf, c1, W1b, b1, o1bf, lf2out, nullptr, nullptr);

    // 3) conv2 GEMM: [M, 2DH] x [2DH, D] -> y = o2 + x (f32, into d_out)
    gemm2tap<DH, 2><<<dim3(MM / 256, DD / 256), 512, 0, stream>>>(
        o1bf, c2, W2b, b2, nullptr, nullptr, x, out);

    // 4) RMSNorm in place + lf1 cache copy
    rmsnorm_inplace<<<MM, 256, 0, stream>>>(out, lnw);
    lf1_copy<<<BB * DD / 256, 256, 0, stream>>>(x, lf1out);
}